// Round 1
// 116.737 us; speedup vs baseline: 1.0921x; 1.0921x over previous
//
#include <hip/hip_runtime.h>
#include <math.h>

#define BLOCK 256
#define GRID  2048   // 2048 blocks x 4 waves = 8192 waves = 32/CU on 256 CUs (exact fill)

// err contribution (positive softplus; final sign folded into scale):
// reference err = lab==1 ? s-lse : lab==2 ? a-lse : 0
//   lab==1: s-lse = -log(1+exp(a-s)) = -softplus(a-s)
//   lab==2: a-lse = -softplus(s-a)
// output = -mean(err) = mean(softplus(d) over lab in {1,2}) / B
__device__ __forceinline__ float sp_term(float s, float a, int lab) {
    float d  = (lab == 1) ? (a - s) : (s - a);
    float ad = fabsf(d);
    float t  = __expf(-ad);                       // v_mul(log2e) + v_exp
    float sp = fmaxf(d, 0.0f) + __logf(1.0f + t); // stable softplus
    return (lab != 0) ? sp : 0.0f;                // lab in {0,1,2}
}

// THEORY-ROUND CHANGE: the old epilogue fired 2048 device-scope atomicAdds at
// ONE address in a burst (all blocks co-resident, identical work -> synchronized
// finish). Cross-XCD same-line atomic serialization = ~30us drain appended to an
// ~18us streaming phase (explains VALUBusy 11%, Occupancy ~45%, BW 2.1 TB/s avg).
// Fix: plain per-block partial store to d_ws (disjoint addresses), then a tiny
// second dispatch reduces 2048 floats and OVERWRITES out (no atomic, no
// dependence on the 0xAA poison value). Memory loop kept byte-identical for
// clean A/B attribution. USE_ATOMIC=true path retained as fallback if ws_size
// is too small.
template <bool USE_ATOMIC>
__global__ __launch_bounds__(BLOCK) void Loss_Labels_34213709479939_kernel(
        const float* __restrict__ syn,
        const float* __restrict__ ant,
        const int*   __restrict__ lab,
        float* __restrict__ dst,      // USE_ATOMIC: out scalar; else: partials[GRID]
        int n_vec,                    // number of float4 groups (B/4)
        float scale)                  // +1/B (sign already folded)
{
    const float4* __restrict__ s4 = (const float4*)syn;
    const float4* __restrict__ a4 = (const float4*)ant;
    const int4*   __restrict__ l4 = (const int4*)lab;

    const int idx    = blockIdx.x * BLOCK + threadIdx.x;
    const int stride = GRID * BLOCK;
    const int iters  = n_vec / stride;       // 4 full iterations at B=2^23
    float acc = 0.0f;

    #pragma unroll 4
    for (int k = 0; k < iters; ++k) {
        int i = idx + k * stride;
        float4 s = s4[i];
        float4 a = a4[i];
        int4   l = l4[i];
        acc += sp_term(s.x, a.x, l.x);
        acc += sp_term(s.y, a.y, l.y);
        acc += sp_term(s.z, a.z, l.z);
        acc += sp_term(s.w, a.w, l.w);
    }
    // tail (empty at B=2^23, kept for generality)
    int i = iters * stride + idx;
    if (i < n_vec) {
        float4 s = s4[i];
        float4 a = a4[i];
        int4   l = l4[i];
        acc += sp_term(s.x, a.x, l.x);
        acc += sp_term(s.y, a.y, l.y);
        acc += sp_term(s.z, a.z, l.z);
        acc += sp_term(s.w, a.w, l.w);
    }

    // wave-64 down-reduction
    #pragma unroll
    for (int off = 32; off > 0; off >>= 1)
        acc += __shfl_down(acc, off, 64);

    __shared__ float smem[BLOCK / 64];
    int lane = threadIdx.x & 63;
    int wid  = threadIdx.x >> 6;
    if (lane == 0) smem[wid] = acc;
    __syncthreads();

    if (threadIdx.x == 0) {
        float t = smem[0] + smem[1] + smem[2] + smem[3];
        if (USE_ATOMIC) {
            atomicAdd(dst, t * scale);           // legacy contended path
        } else {
            dst[blockIdx.x] = t;                 // disjoint address: no contention,
        }                                        // fire-and-forget store
    }
}

// Second dispatch: sum GRID=2048 partials (8 KiB, L2-hot) and overwrite out.
// One block, 4 waves, 8 coalesced loads/thread. Deterministic reduction order.
__global__ __launch_bounds__(BLOCK) void Loss_Labels_34213709479939_reduce(
        const float* __restrict__ partials,
        float* __restrict__ out,
        float scale)
{
    float acc = 0.0f;
    #pragma unroll
    for (int i = threadIdx.x; i < GRID; i += BLOCK)
        acc += partials[i];

    #pragma unroll
    for (int off = 32; off > 0; off >>= 1)
        acc += __shfl_down(acc, off, 64);

    __shared__ float smem[BLOCK / 64];
    int lane = threadIdx.x & 63;
    int wid  = threadIdx.x >> 6;
    if (lane == 0) smem[wid] = acc;
    __syncthreads();

    if (threadIdx.x == 0)
        out[0] = (smem[0] + smem[1] + smem[2] + smem[3]) * scale; // plain store
}                                                                // overwrites poison

extern "C" void kernel_launch(void* const* d_in, const int* in_sizes, int n_in,
                              void* d_out, int out_size, void* d_ws, size_t ws_size,
                              hipStream_t stream) {
    const float* syn = (const float*)d_in[0];
    const float* ant = (const float*)d_in[1];
    const int*   lab = (const int*)d_in[2];
    float*       out = (float*)d_out;

    const int B     = in_sizes[0];       // (B,1) flat = B elements
    const int n_vec = B / 4;             // B = 2^23, divisible by 4
    const float scale = 1.0f / (float)B; // -mean(err) == +mean(softplus)

    if (ws_size >= GRID * sizeof(float)) {
        float* partials = (float*)d_ws;
        Loss_Labels_34213709479939_kernel<false><<<GRID, BLOCK, 0, stream>>>(
            syn, ant, lab, partials, n_vec, scale);
        Loss_Labels_34213709479939_reduce<<<1, BLOCK, 0, stream>>>(
            partials, out, scale);
    } else {
        // fallback: contended-atomic single dispatch (original behavior)
        Loss_Labels_34213709479939_kernel<true><<<GRID, BLOCK, 0, stream>>>(
            syn, ant, lab, out, n_vec, scale);
    }
}

// Round 3
// 114.324 us; speedup vs baseline: 1.1151x; 1.0211x over previous
//
#include <hip/hip_runtime.h>
#include <math.h>

#define BLOCK 256
#define GRID  2048   // 2048 blocks x 4 waves = 8192 waves = 32/CU on 256 CUs (exact fill)

// err contribution (positive softplus; final sign folded into scale):
//   lab==1: s-lse = -softplus(a-s);  lab==2: a-lse = -softplus(s-a)
// output = -mean(err) = mean(softplus(d) over lab in {1,2}) / B
__device__ __forceinline__ float sp_term(float s, float a, int lab) {
    float d  = (lab == 1) ? (a - s) : (s - a);
    float ad = fabsf(d);
    float t  = __expf(-ad);                       // v_mul(log2e) + v_exp
    float sp = fmaxf(d, 0.0f) + __logf(1.0f + t); // stable softplus
    return (lab != 0) ? sp : 0.0f;                // lab in {0,1,2}
}

__device__ __forceinline__ float sp4(float4 s, float4 a, int4 l) {
    return sp_term(s.x, a.x, l.x) + sp_term(s.y, a.y, l.y)
         + sp_term(s.z, a.z, l.z) + sp_term(s.w, a.w, l.w);
}

// ROUND-3: resubmit of round-2 experiment (container failed twice -> no data).
// Only change: the k==3 pipeline step no longer rotates uninitialized s1/a1/l1
// into the loop-carried registers (was dead-value UB; now guarded).
//
// Standing theory: harness poison-fills of d_ws (5 x ~41us fillBufferAligned at
// 82% HBM peak in round-1 profile) overlap our kernel and eat HBM BW; our
// controllable slack is latency overlap + epilogue cost.
//  (a) distance-1 software pipeline on the static iters==4 path: next 3 loads
//      in flight before the exp/log chain (tests model (i) scheduling-limit),
//  (b) reduce dispatch = one wave, float4 loads, no smem/barrier.
// Single-dispatch "last block" merges REJECTED: ticket/spin protocols depend on
// d_ws initial-value semantics (0xAA poison in timed graph vs unknown in the
// correctness call) -> stale-read/deadlock risk.
template <bool USE_ATOMIC>
__global__ __launch_bounds__(BLOCK) void Loss_Labels_34213709479939_kernel(
        const float* __restrict__ syn,
        const float* __restrict__ ant,
        const int*   __restrict__ lab,
        float* __restrict__ dst,      // USE_ATOMIC: out scalar; else: partials[GRID]
        int n_vec,                    // number of float4 groups (B/4)
        float scale)                  // +1/B (sign already folded)
{
    const float4* __restrict__ s4 = (const float4*)syn;
    const float4* __restrict__ a4 = (const float4*)ant;
    const int4*   __restrict__ l4 = (const int4*)lab;

    const int idx    = blockIdx.x * BLOCK + threadIdx.x;
    const int stride = GRID * BLOCK;
    float acc = 0.0f;

    if (n_vec == 4 * stride) {
        // static fast path, B = 2^23: exactly 4 float4-iterations per thread,
        // software-pipelined with prefetch distance 1 (~24 extra VGPRs, still
        // well under the 64-VGPR/full-occupancy cliff -> 32 waves/CU).
        float4 s0 = s4[idx];
        float4 a0 = a4[idx];
        int4   l0 = l4[idx];
        #pragma unroll
        for (int k = 0; k < 4; ++k) {
            float4 s1, a1; int4 l1;
            if (k < 3) {
                int j = idx + (k + 1) * stride;
                s1 = s4[j];
                a1 = a4[j];
                l1 = l4[j];
            }
            acc += sp4(s0, a0, l0);   // exp/log chain overlaps next loads
            if (k < 3) { s0 = s1; a0 = a1; l0 = l1; }
        }
    } else {
        // generic path (any B divisible by 4)
        const int iters = n_vec / stride;
        for (int k = 0; k < iters; ++k) {
            int i = idx + k * stride;
            acc += sp4(s4[i], a4[i], l4[i]);
        }
        int i = iters * stride + idx;
        if (i < n_vec)
            acc += sp4(s4[i], a4[i], l4[i]);
    }

    // wave-64 down-reduction
    #pragma unroll
    for (int off = 32; off > 0; off >>= 1)
        acc += __shfl_down(acc, off, 64);

    __shared__ float smem[BLOCK / 64];
    int lane = threadIdx.x & 63;
    int wid  = threadIdx.x >> 6;
    if (lane == 0) smem[wid] = acc;
    __syncthreads();

    if (threadIdx.x == 0) {
        float t = smem[0] + smem[1] + smem[2] + smem[3];
        if (USE_ATOMIC) {
            atomicAdd(dst, t * scale);           // legacy contended path
        } else {
            dst[blockIdx.x] = t;                 // disjoint address, no contention
        }
    }
}

// Second dispatch: sum GRID=2048 partials (8 KiB, L2/L3-hot) and overwrite out
// (also erases the 0xAA poison). One wave, float4 loads, no smem, no barrier.
__global__ __launch_bounds__(64) void Loss_Labels_34213709479939_reduce(
        const float* __restrict__ partials,
        float* __restrict__ out,
        float scale)
{
    const float4* __restrict__ p4 = (const float4*)partials;  // 512 float4
    float acc = 0.0f;
    #pragma unroll
    for (int i = 0; i < (GRID / 4) / 64; ++i) {               // 8 per lane
        float4 v = p4[threadIdx.x + 64 * i];
        acc += (v.x + v.y) + (v.z + v.w);
    }
    #pragma unroll
    for (int off = 32; off > 0; off >>= 1)
        acc += __shfl_down(acc, off, 64);
    if (threadIdx.x == 0)
        out[0] = acc * scale;                                 // plain store
}

extern "C" void kernel_launch(void* const* d_in, const int* in_sizes, int n_in,
                              void* d_out, int out_size, void* d_ws, size_t ws_size,
                              hipStream_t stream) {
    const float* syn = (const float*)d_in[0];
    const float* ant = (const float*)d_in[1];
    const int*   lab = (const int*)d_in[2];
    float*       out = (float*)d_out;

    const int B     = in_sizes[0];       // (B,1) flat = B elements
    const int n_vec = B / 4;             // B = 2^23, divisible by 4
    const float scale = 1.0f / (float)B; // -mean(err) == +mean(softplus)

    if (ws_size >= GRID * sizeof(float)) {
        float* partials = (float*)d_ws;
        Loss_Labels_34213709479939_kernel<false><<<GRID, BLOCK, 0, stream>>>(
            syn, ant, lab, partials, n_vec, scale);
        Loss_Labels_34213709479939_reduce<<<1, 64, 0, stream>>>(
            partials, out, scale);
    } else {
        // fallback: contended-atomic single dispatch (original behavior)
        Loss_Labels_34213709479939_kernel<true><<<GRID, BLOCK, 0, stream>>>(
            syn, ant, lab, out, n_vec, scale);
    }
}